// Round 6
// baseline (125.633 us; speedup 1.0000x reference)
//
#include <hip/hip_runtime.h>
#include <math.h>

#define N 1024
#define B_ 8
#define T_ 256
#define R_ 2        // delay rows per FFT block
#define NREP 4
#define GX 257      // blocks 0..255: m=2*blk,2*blk+1 (0..511); block 256: m=512

// ws layout (float index)
#define OFF_SF      0        // 1024 x float2 (interleaved)          [0, 2048)
#define OFF_TW      2048     // 4 stages x 256 x 8 floats            [2048, 10240)
#define OFF_ROWSUM  10240    // 8 x 1024                             [10240, 18432)
#define ZERO_START  18432
#define OFF_COLSUMM 18432    // 1024
#define OFF_SUMM2   19456
#define OFF_MAXM    19457
#define OFF_SUMMT   19464    // 8
#define OFF_SUMTT   19472    // 8
#define OFF_COLT    20480    // 8 batches x NREP x 1024              [20480, 53248)
#define WS_END      (OFF_COLT + B_ * NREP * N)

// per-transition LDS swizzles (bijective XOR of high addr bits into bank bits)
#define S1(a) ((a) ^ (((a) >> 2) & 0x10))
#define S2(a) ((a) ^ (((a) >> 3) & 0x0C))
#define S3(a) ((a) ^ (((a) >> 5) & 0x07))
#define S4(a) ((a) ^ (((a) >> 5) & 0x07))

__device__ __forceinline__ float wave_sum(float v) {
    #pragma unroll
    for (int o = 32; o > 0; o >>= 1) v += __shfl_down(v, o, 64);
    return v;
}
__device__ __forceinline__ float wave_max(float v) {
    #pragma unroll
    for (int o = 32; o > 0; o >>= 1) v = fmaxf(v, __shfl_down(v, o, 64));
    return v;
}

__device__ __forceinline__ void load_tw(float tw[6], const float* __restrict__ p) {
    float4 v = *(const float4*)p;
    float2 w = *(const float2*)(p + 4);
    tw[0] = v.x; tw[1] = v.y; tw[2] = v.z; tw[3] = v.w; tw[4] = w.x; tw[5] = w.y;
}

// forward radix-4 DIF butterfly + twiddles (W^pos, W^2pos, W^3pos), in place
__device__ __forceinline__ void bfly4(float xr[4], float xi[4], const float tw[6]) {
    float t0r = xr[0] + xr[2], t0i = xi[0] + xi[2];
    float t1r = xr[0] - xr[2], t1i = xi[0] - xi[2];
    float t2r = xr[1] + xr[3], t2i = xi[1] + xi[3];
    float t3r = xr[1] - xr[3], t3i = xi[1] - xi[3];
    float y1r = t1r + t3i, y1i = t1i - t3r;
    float y2r = t0r - t2r, y2i = t0i - t2i;
    float y3r = t1r - t3i, y3i = t1i + t3r;
    xr[0] = t0r + t2r;            xi[0] = t0i + t2i;
    xr[1] = y1r * tw[0] - y1i * tw[1]; xi[1] = y1r * tw[1] + y1i * tw[0];
    xr[2] = y2r * tw[2] - y2i * tw[3]; xi[2] = y2r * tw[3] + y2i * tw[2];
    xr[3] = y3r * tw[4] - y3i * tw[5]; xi[3] = y3r * tw[5] + y3i * tw[4];
}

// sf + twiddle tables + zero accumulators + zero out: 4 blocks x 256 threads
__global__ __launch_bounds__(T_) void k_prep(float* ws, float* out) {
    const int e = blockIdx.x * T_ + threadIdx.x;   // 0..1023
    {
        double ang = -2.0 * 337.927 * 1.5 * (double)(e - 512);
        double s, c;
        sincos(ang, &s, &c);
        ws[OFF_SF + 2 * e] = (float)c;
        ws[OFF_SF + 2 * e + 1] = (float)s;
    }
    {
        int s = e >> 8, tt = e & 255;
        int h = 256 >> (2 * s);
        int pos = tt & (h - 1);
        int step = 1 << (2 * s);
        double a1 = -2.0 * M_PI * (double)(pos * step) / 1024.0;
        double s1, c1, s2, c2, s3, c3;
        sincos(a1, &s1, &c1);
        sincos(2.0 * a1, &s2, &c2);
        sincos(3.0 * a1, &s3, &c3);
        float* p = ws + OFF_TW + e * 8;
        p[0] = (float)c1; p[1] = (float)s1;
        p[2] = (float)c2; p[3] = (float)s2;
        p[4] = (float)c3; p[5] = (float)s3;
        p[6] = 0.f; p[7] = 0.f;
    }
    for (int j = ZERO_START + e; j < WS_END; j += 4 * T_) ws[j] = 0.f;
    if (e == 0) out[0] = 0.f;
}

// One FFT row: product from global pred + 5 radix-4 stages through LDS
// (X0 -> X1 -> X0 -> X1 -> X0), magnitudes land in X0[S4(.)].
// Accumulates rowsum into red[rslot], colreg/mt/tt in registers.
__device__ __forceinline__ void fft_row(
    int t, int m, float w,
    const float* __restrict__ pr,
    const float sfr[4], const float sfi[4],
    const float tw0[6], const float tw1[6], const float tw2[6], const float tw3[6],
    float* __restrict__ X0r, float* __restrict__ X0i,
    float* __restrict__ X1r, float* __restrict__ X1i,
    const float* __restrict__ M, int mm,
    float colreg[4], float& mtacc, float& ttacc,
    float red[][4], int rslot)
{
    float xr[4], xi[4];

    // product + stage 0 (h=256), in registers
    #pragma unroll
    for (int q = 0; q < 4; ++q) {
        int j = t + T_ * q;
        int s = (j - m + 512) & (N - 1);
        float ar = pr[j], ai = pr[N + j];
        float br = pr[s], bi = pr[N + s];
        float p_r = ar * br - ai * bi;
        float p_i = ar * bi + ai * br;
        xr[q] = p_r * sfr[q] - p_i * sfi[q];
        xi[q] = p_r * sfi[q] + p_i * sfr[q];
    }
    bfly4(xr, xi, tw0);
    #pragma unroll
    for (int q = 0; q < 4; ++q) { int a = t + 256 * q; X0r[a] = xr[q]; X0i[a] = xi[q]; }
    __syncthreads();

    // stage 1 (h=64): X0 -> X1 (S1)
    {
        int base = ((t >> 6) << 8) | (t & 63);
        #pragma unroll
        for (int q = 0; q < 4; ++q) { int a = base + (q << 6); xr[q] = X0r[a]; xi[q] = X0i[a]; }
        bfly4(xr, xi, tw1);
        #pragma unroll
        for (int q = 0; q < 4; ++q) { int a = S1(base + (q << 6)); X1r[a] = xr[q]; X1i[a] = xi[q]; }
    }
    __syncthreads();

    // stage 2 (h=16): X1 (S1) -> X0 (S2)
    {
        int base = ((t >> 4) << 6) | (t & 15);
        #pragma unroll
        for (int q = 0; q < 4; ++q) { int a = S1(base + (q << 4)); xr[q] = X1r[a]; xi[q] = X1i[a]; }
        bfly4(xr, xi, tw2);
        #pragma unroll
        for (int q = 0; q < 4; ++q) { int a = S2(base + (q << 4)); X0r[a] = xr[q]; X0i[a] = xi[q]; }
    }
    __syncthreads();

    // stage 3 (h=4): X0 (S2) -> X1 (S3)
    {
        int base = ((t >> 2) << 4) | (t & 3);
        #pragma unroll
        for (int q = 0; q < 4; ++q) { int a = S2(base + (q << 2)); xr[q] = X0r[a]; xi[q] = X0i[a]; }
        bfly4(xr, xi, tw3);
        #pragma unroll
        for (int q = 0; q < 4; ++q) { int a = S3(base + (q << 2)); X1r[a] = xr[q]; X1i[a] = xi[q]; }
    }
    __syncthreads();

    // stage 4 (h=1, W=1): X1 (S3) -> magnitudes -> X0 (S4)
    {
        int base = t << 2;
        #pragma unroll
        for (int q = 0; q < 4; ++q) { int a = S3(base + q); xr[q] = X1r[a]; xi[q] = X1i[a]; }
        float t0r = xr[0] + xr[2], t0i = xi[0] + xi[2];
        float t1r = xr[0] - xr[2], t1i = xi[0] - xi[2];
        float t2r = xr[1] + xr[3], t2i = xi[1] + xi[3];
        float t3r = xr[1] - xr[3], t3i = xi[1] - xi[3];
        float yr[4], yi[4];
        yr[0] = t0r + t2r; yi[0] = t0i + t2i;
        yr[1] = t1r + t3i; yi[1] = t1i - t3r;
        yr[2] = t0r - t2r; yi[2] = t0i - t2i;
        yr[3] = t1r - t3i; yi[3] = t1i + t3r;
        int r4t = ((t & 3) << 6) | (((t >> 2) & 3) << 4) | (((t >> 4) & 3) << 2) | ((t >> 6) & 3);
        #pragma unroll
        for (int q = 0; q < 4; ++q) {
            int c = ((q << 8) | r4t) ^ 512;
            X0r[S4(c)] = 1.5f * sqrtf(yr[q] * yr[q] + yi[q] * yi[q]);
        }
    }
    __syncthreads();

    // reductions (no trailing barrier: next row's stage-0 targets the other buffer)
    {
        const float* Mrow = M + (size_t)m * N;
        const float* Mrow2 = M + (size_t)mm * N;
        float rs = 0.f;
        #pragma unroll
        for (int q = 0; q < 4; ++q) {
            int cc = t + 256 * q;
            float v = X0r[S4(cc)];
            rs += v;
            ttacc += w * v * v;
            float msum = Mrow[cc];
            if (mm != m) msum += Mrow2[cc];
            mtacc += msum * v;
            colreg[q] += w * v;
        }
        rs = wave_sum(rs);
        if ((t & 63) == 0) red[rslot][t >> 6] = rs;
    }
}

// grid (GX, B_+1):
//   y < B_ : FFT blocks — R_ delay rows of batch y, exploiting T[m]==T[1024-m]
//   y == B_: blocks 0..63 compute M stats (colsumM / sumM2 / maxM), rest exit
__global__ __launch_bounds__(T_, 8) void k_row(const float* __restrict__ pred,
                                               const float* __restrict__ M,
                                               float* __restrict__ ws) {
    __shared__ float Ar[N], Ai[N], Br[N], Bi[N];
    __shared__ float red[R_ + 2][4];
    const int t = threadIdx.x;
    const int blk = blockIdx.x;
    const int b = blockIdx.y;
    const int wid = t >> 6, lane = t & 63;

    if (b == B_) {
        // ---- M-stats slice (runs concurrently with the FFT blocks) ----
        if (blk >= 64) return;
        const int r0 = blk * 16;
        float cs[4] = {0.f, 0.f, 0.f, 0.f};
        float sq = 0.f, mx = 0.f;
        for (int r = 0; r < 16; ++r) {
            const float* row = M + (size_t)(r0 + r) * N;
            #pragma unroll
            for (int q = 0; q < 4; ++q) {
                float v = row[t + T_ * q];
                cs[q] += v;
                sq += v * v;
                mx = fmaxf(mx, v);
            }
        }
        #pragma unroll
        for (int q = 0; q < 4; ++q) atomicAdd(&ws[OFF_COLSUMM + t + T_ * q], cs[q]);
        sq = wave_sum(sq);
        mx = wave_max(mx);
        if (lane == 0) { red[0][wid] = sq; red[1][wid] = mx; }
        __syncthreads();
        if (t == 0) {
            atomicAdd(&ws[OFF_SUMM2], red[0][0] + red[0][1] + red[0][2] + red[0][3]);
            float X = fmaxf(fmaxf(red[1][0], red[1][1]), fmaxf(red[1][2], red[1][3]));
            atomicMax((unsigned int*)ws + OFF_MAXM, __float_as_uint(X));
        }
        return;
    }

    // ---- FFT slice ----
    const int nr = (blk == GX - 1) ? 1 : R_;
    const int m0 = blk * R_;
    const float* pr = pred + (size_t)b * 2 * N;

    // sf + twiddles live in registers for the whole block
    float sfr[4], sfi[4];
    {
        const float2* sf2 = (const float2*)(ws + OFF_SF);
        #pragma unroll
        for (int q = 0; q < 4; ++q) {
            float2 sv = sf2[t + T_ * q];
            sfr[q] = sv.x; sfi[q] = sv.y;
        }
    }
    float tw0[6], tw1[6], tw2[6], tw3[6];
    load_tw(tw0, ws + OFF_TW + (size_t)t * 8);
    load_tw(tw1, ws + OFF_TW + (size_t)(256 + t) * 8);
    load_tw(tw2, ws + OFF_TW + (size_t)(512 + t) * 8);
    load_tw(tw3, ws + OFF_TW + (size_t)(768 + t) * 8);

    float colreg[4] = {0.f, 0.f, 0.f, 0.f};
    float mtacc = 0.f, ttacc = 0.f;

    {
        const int m = m0;
        const int mm = (N - m) & (N - 1);
        const float w = (mm == m) ? 1.f : 2.f;
        fft_row(t, m, w, pr, sfr, sfi, tw0, tw1, tw2, tw3,
                Ar, Ai, Br, Bi, M, mm, colreg, mtacc, ttacc, red, 0);
    }
    if (nr == R_) {
        const int m = m0 + 1;
        const int mm = (N - m) & (N - 1);
        // parity flip: stage-0 writes B while row 0's reductions read A
        fft_row(t, m, 2.f, pr, sfr, sfi, tw0, tw1, tw2, tw3,
                Br, Bi, Ar, Ai, M, mm, colreg, mtacc, ttacc, red, 1);
    }

    // block epilogue: flush colreg (1 atomic/column), rowsums, reduced MT/TT
    {
        float* colT = ws + OFF_COLT + (size_t)(b * NREP + (blk & (NREP - 1))) * N;
        #pragma unroll
        for (int q = 0; q < 4; ++q) {
            atomicAdd(&colT[t + 256 * q], colreg[q]);
        }
        float mt = wave_sum(mtacc);
        float tt2 = wave_sum(ttacc);
        if (lane == 0) { red[R_][wid] = mt; red[R_ + 1][wid] = tt2; }
        __syncthreads();
        if (t == 0) {
            for (int r = 0; r < nr; ++r) {
                int m = m0 + r, mm = (N - m) & (N - 1);
                float R = red[r][0] + red[r][1] + red[r][2] + red[r][3];
                ws[OFF_ROWSUM + b * N + m] = R;
                if (mm != m) ws[OFF_ROWSUM + b * N + mm] = R;
            }
            atomicAdd(&ws[OFF_SUMMT + b], red[R_][0] + red[R_][1] + red[R_][2] + red[R_][3]);
            atomicAdd(&ws[OFF_SUMTT + b], red[R_ + 1][0] + red[R_ + 1][1] + red[R_ + 1][2] + red[R_ + 1][3]);
        }
    }
}

__global__ __launch_bounds__(T_) void k_final(float* ws, float* out) {
    __shared__ double redn[4], redd[4];
    const int b = blockIdx.x;
    const int t = threadIdx.x;
    const int wid = t >> 6, lane = t & 63;
    const float* rowsum = ws + OFF_ROWSUM + (size_t)b * N;
    double num = 0.0, den = 0.0;
    #pragma unroll
    for (int q = 0; q < 4; ++q) {
        int j = t + 256 * q;
        double r = (double)rowsum[j];
        float ct = 0.f;
        #pragma unroll
        for (int rep = 0; rep < NREP; ++rep)
            ct += ws[OFF_COLT + (size_t)(b * NREP + rep) * N + j];
        num += (double)ws[OFF_COLSUMM + j] * r;
        den += (double)ct * r;
    }
    #pragma unroll
    for (int o = 32; o > 0; o >>= 1) {
        num += __shfl_down(num, o, 64);
        den += __shfl_down(den, o, 64);
    }
    if (lane == 0) { redn[wid] = num; redd[wid] = den; }
    __syncthreads();
    if (t == 0) {
        double NUM = redn[0] + redn[1] + redn[2] + redn[3];
        double DEN = redd[0] + redd[1] + redd[2] + redd[3];
        double mu = NUM / DEN;
        double r = (double)ws[OFF_SUMM2] - 2.0 * mu * (double)ws[OFF_SUMMT + b]
                 + mu * mu * (double)ws[OFF_SUMTT + b];
        float mx = ws[OFF_MAXM];  // float bits written via uint atomicMax
        double norm = 1048576.0 * (double)mx * (double)mx;
        atomicAdd(out, (float)(sqrt(r / norm) / 8.0));
    }
}

extern "C" void kernel_launch(void* const* d_in, const int* in_sizes, int n_in,
                              void* d_out, int out_size, void* d_ws, size_t ws_size,
                              hipStream_t stream) {
    const float* pred = (const float*)d_in[0];   // [8, 2048]
    const float* M = (const float*)d_in[2];      // [1024, 1024]
    float* ws = (float*)d_ws;
    float* out = (float*)d_out;

    k_prep<<<4, T_, 0, stream>>>(ws, out);
    dim3 grid(GX, B_ + 1);
    k_row<<<grid, T_, 0, stream>>>(pred, M, ws);
    k_final<<<B_, T_, 0, stream>>>(ws, out);
}